// Round 1
// baseline (248.963 us; speedup 1.0000x reference)
//
#include <hip/hip_runtime.h>
#include <math.h>

#define DEVINL __device__ __forceinline__

// Deterministic block reduction of two double accumulators.
// All threads must call; result valid in thread 0 only.
template<int NWAVES>
DEVINL void block_reduce_2d(double& a, double& b) {
  #pragma unroll
  for (int off = 32; off > 0; off >>= 1) {
    a += __shfl_down(a, off, 64);
    b += __shfl_down(b, off, 64);
  }
  __shared__ double sa[NWAVES], sb[NWAVES];
  const int tid = threadIdx.x;
  const int wid = tid >> 6;
  if ((tid & 63) == 0) { sa[wid] = a; sb[wid] = b; }
  __syncthreads();
  if (tid == 0) {
    double ta = 0.0, tb = 0.0;
    #pragma unroll
    for (int w = 0; w < NWAVES; ++w) { ta += sa[w]; tb += sb[w]; }
    a = ta; b = tb;
  }
}

// ---------------- Layer 1: x(16,1,196,3) * w1(128,1,6,1) s=(2,1) -> h1(16,128,96,3), fused BN+ReLU
__global__ __launch_bounds__(256) void k_conv1(
    const float* __restrict__ x, const float* __restrict__ w1,
    const float* __restrict__ g1, const float* __restrict__ b1,
    float* __restrict__ h1) {
  const int co = blockIdx.x;    // 128
  const int tid = threadIdx.x;  // 256
  float wv[6];
  #pragma unroll
  for (int i = 0; i < 6; ++i) wv[i] = w1[co * 6 + i];

  float vals[18];               // 4608 positions / 256 threads
  double s = 0.0, sq = 0.0;
  #pragma unroll
  for (int k = 0; k < 18; ++k) {
    const int p = tid + k * 256;          // (n, ho, wo)
    const int n = p / 288;
    const int r = p - n * 288;
    const int ho = r / 3;
    const int wo = r - ho * 3;
    const float* xb = x + n * 588 + (2 * ho) * 3 + wo;
    float acc = 0.f;
    #pragma unroll
    for (int i = 0; i < 6; ++i) acc += fabsf(xb[i * 3] - wv[i]);
    const float v = -acc;
    vals[k] = v;
    s += (double)v;
    sq += (double)v * (double)v;
  }
  block_reduce_2d<4>(s, sq);
  __shared__ float ssc, ssh;
  if (tid == 0) {
    const double mean = s * (1.0 / 4608.0);
    const double var  = sq * (1.0 / 4608.0) - mean * mean;
    const float rstd = (float)rsqrt(var + 1e-5);
    const float sc = g1[co] * rstd;
    ssc = sc;
    ssh = b1[co] - (float)mean * sc;
  }
  __syncthreads();
  const float sc = ssc, sh = ssh;
  #pragma unroll
  for (int k = 0; k < 18; ++k) {
    const int p = tid + k * 256;
    const int n = p / 288;
    const int r = p - n * 288;
    const int ho = r / 3;
    const int wo = r - ho * 3;
    h1[((n * 128 + co) * 96 + ho) * 3 + wo] = fmaxf(0.f, fmaf(vals[k], sc, sh));
  }
}

// ---------------- Layer 2: h1(16,128,96,3) * w2(256,128,6,1) s=(2,1) -> h2(16,256,46,3), fused BN+ReLU
// One block per co (256 blocks, 384 threads). Thread job = (n, ho-pair) covering 6 outputs.
__global__ __launch_bounds__(384) void k_conv2(
    const float* __restrict__ h1, const float* __restrict__ w2,
    const float* __restrict__ g2, const float* __restrict__ b2,
    float* __restrict__ h2) {
  const int co = blockIdx.x;    // 256
  const int tid = threadIdx.x;  // 384, jobs = 16*23 = 368
  const bool active = tid < 368;
  int n = 0, hp = 0;
  if (active) { n = tid / 23; hp = tid - n * 23; }

  float acc[6] = {0.f, 0.f, 0.f, 0.f, 0.f, 0.f};
  if (active) {
    const float4* xb = (const float4*)(h1 + n * 36864 + hp * 12); // 24-float window, 16B aligned
    const float* wb = w2 + co * 768;
    for (int ci = 0; ci < 128; ++ci) {
      float wv[6];
      #pragma unroll
      for (int i = 0; i < 6; ++i) wv[i] = wb[ci * 6 + i];   // wave-uniform -> scalar loads
      float xf[24];
      #pragma unroll
      for (int t = 0; t < 6; ++t) {
        const float4 q = xb[ci * 72 + t];
        xf[4 * t + 0] = q.x; xf[4 * t + 1] = q.y; xf[4 * t + 2] = q.z; xf[4 * t + 3] = q.w;
      }
      #pragma unroll
      for (int po = 0; po < 2; ++po)
        #pragma unroll
        for (int wo = 0; wo < 3; ++wo)
          #pragma unroll
          for (int i = 0; i < 6; ++i)
            acc[po * 3 + wo] += fabsf(xf[(2 * po + i) * 3 + wo] - wv[i]);
    }
  }
  double s = 0.0, sq = 0.0;
  #pragma unroll
  for (int k = 0; k < 6; ++k) {
    const float v = -acc[k];
    acc[k] = v;
    s += (double)v;
    sq += (double)v * (double)v;
  }
  block_reduce_2d<6>(s, sq);
  __shared__ float ssc, ssh;
  if (tid == 0) {
    const double mean = s * (1.0 / 2208.0);
    const double var  = sq * (1.0 / 2208.0) - mean * mean;
    const float rstd = (float)rsqrt(var + 1e-5);
    const float sc = g2[co] * rstd;
    ssc = sc;
    ssh = b2[co] - (float)mean * sc;
  }
  __syncthreads();
  const float sc = ssc, sh = ssh;
  if (active) {
    #pragma unroll
    for (int po = 0; po < 2; ++po)
      #pragma unroll
      for (int wo = 0; wo < 3; ++wo) {
        const int ho = 2 * hp + po;
        h2[((n * 256 + co) * 46 + ho) * 3 + wo] =
            fmaxf(0.f, fmaf(acc[po * 3 + wo], sc, sh));
      }
  }
}

// ---------------- Layer 3: h2(16,256,46,3) * w3(384,256,6,2) s=(2,1) -> h3(16,384,21,2), fused BN+ReLU
// One block per co (384 blocks, 384 threads). Thread job = (n, ho) covering 2 outputs (wo=0,1).
__global__ __launch_bounds__(384) void k_conv3(
    const float* __restrict__ h2, const float* __restrict__ w3,
    const float* __restrict__ g3, const float* __restrict__ b3,
    float* __restrict__ h3) {
  const int co = blockIdx.x;    // 384
  const int tid = threadIdx.x;  // 384, jobs = 16*21 = 336
  const bool active = tid < 336;
  int n = 0, ho = 0;
  if (active) { n = tid / 21; ho = tid - n * 21; }

  float acc[2] = {0.f, 0.f};
  if (active) {
    const float2* xb = (const float2*)(h2 + n * 35328 + ho * 6); // 18-float window, 8B aligned
    const float* wb = w3 + co * 3072;
    for (int ci = 0; ci < 256; ++ci) {
      float wv[12];
      #pragma unroll
      for (int i = 0; i < 12; ++i) wv[i] = wb[ci * 12 + i];  // wave-uniform
      float xf[18];
      #pragma unroll
      for (int t = 0; t < 9; ++t) {
        const float2 q = xb[ci * 69 + t];
        xf[2 * t + 0] = q.x; xf[2 * t + 1] = q.y;
      }
      #pragma unroll
      for (int wo = 0; wo < 2; ++wo)
        #pragma unroll
        for (int i = 0; i < 6; ++i)
          #pragma unroll
          for (int jj = 0; jj < 2; ++jj)
            acc[wo] += fabsf(xf[i * 3 + wo + jj] - wv[i * 2 + jj]);
    }
  }
  double s = 0.0, sq = 0.0;
  #pragma unroll
  for (int k = 0; k < 2; ++k) {
    const float v = -acc[k];
    acc[k] = v;
    s += (double)v;
    sq += (double)v * (double)v;
  }
  block_reduce_2d<6>(s, sq);
  __shared__ float ssc, ssh;
  if (tid == 0) {
    const double mean = s * (1.0 / 672.0);
    const double var  = sq * (1.0 / 672.0) - mean * mean;
    const float rstd = (float)rsqrt(var + 1e-5);
    const float sc = g3[co] * rstd;
    ssc = sc;
    ssh = b3[co] - (float)mean * sc;
  }
  __syncthreads();
  const float sc = ssc, sh = ssh;
  if (active) {
    #pragma unroll
    for (int wo = 0; wo < 2; ++wo)
      h3[((n * 384 + co) * 21 + ho) * 2 + wo] = fmaxf(0.f, fmaf(acc[wo], sc, sh));
  }
}

// ---------------- FC: h3 viewed as (16,16128) @ Wfc(6,16128)^T + bfc -> hfc(96)
__global__ __launch_bounds__(256) void k_fc(
    const float* __restrict__ h3, const float* __restrict__ Wfc,
    const float* __restrict__ bfc, float* __restrict__ hfc) {
  const int b = blockIdx.x;     // 96 = 16*6
  const int n = b / 6;
  const int o = b - n * 6;
  const float4* xr = (const float4*)(h3 + n * 16128);
  const float4* wr = (const float4*)(Wfc + o * 16128);
  float s = 0.f;
  for (int k = threadIdx.x; k < 4032; k += 256) {
    const float4 xv = xr[k];
    const float4 wv = wr[k];
    s += xv.x * wv.x + xv.y * wv.y + xv.z * wv.z + xv.w * wv.w;
  }
  double d = (double)s, dummy = 0.0;
  block_reduce_2d<4>(d, dummy);
  if (threadIdx.x == 0) hfc[b] = (float)d + bfc[o];
}

// ---------------- Final: global LayerNorm over 96 values + per-row L2 normalize -> out(16,6)
__global__ __launch_bounds__(128) void k_final(
    const float* __restrict__ hfc, float* __restrict__ out) {
  __shared__ float ys[96];
  __shared__ float params[2];
  const int tid = threadIdx.x;
  const float v = (tid < 96) ? hfc[tid] : 0.f;
  if (tid < 96) ys[tid] = v;
  __syncthreads();
  if (tid == 0) {
    double s = 0.0, sq = 0.0;
    for (int i = 0; i < 96; ++i) { const double t = (double)ys[i]; s += t; sq += t * t; }
    const double mu = s / 96.0;
    const double var = sq / 96.0 - mu * mu;
    params[0] = (float)mu;
    params[1] = (float)rsqrt(var + 1e-5);
  }
  __syncthreads();
  const float y = (v - params[0]) * params[1];
  __syncthreads();
  if (tid < 96) ys[tid] = y;
  __syncthreads();
  if (tid < 96) {
    const int n = tid / 6;
    float ss = 0.f;
    #pragma unroll
    for (int k = 0; k < 6; ++k) { const float t = ys[n * 6 + k]; ss += t * t; }
    const float norm = sqrtf(ss);
    out[tid] = y / fmaxf(norm, 1e-12f);
  }
}

extern "C" void kernel_launch(void* const* d_in, const int* in_sizes, int n_in,
                              void* d_out, int out_size, void* d_ws, size_t ws_size,
                              hipStream_t stream) {
  const float* x   = (const float*)d_in[0];
  const float* w1  = (const float*)d_in[1];
  const float* g1  = (const float*)d_in[2];
  const float* b1  = (const float*)d_in[3];
  const float* w2  = (const float*)d_in[4];
  const float* g2  = (const float*)d_in[5];
  const float* b2  = (const float*)d_in[6];
  const float* w3  = (const float*)d_in[7];
  const float* g3  = (const float*)d_in[8];
  const float* b3  = (const float*)d_in[9];
  const float* Wfc = (const float*)d_in[10];
  const float* bfc = (const float*)d_in[11];

  float* ws  = (float*)d_ws;
  float* h1  = ws;                 // 16*128*96*3 = 589824
  float* h2  = h1 + 589824;        // 16*256*46*3 = 565248
  float* h3  = h2 + 565248;        // 16*384*21*2 = 258048
  float* hfc = h3 + 258048;        // 96
  float* out = (float*)d_out;

  k_conv1<<<128, 256, 0, stream>>>(x, w1, g1, b1, h1);
  k_conv2<<<256, 384, 0, stream>>>(h1, w2, g2, b2, h2);
  k_conv3<<<384, 384, 0, stream>>>(h2, w3, g3, b3, h3);
  k_fc<<<96, 256, 0, stream>>>(h3, Wfc, bfc, hfc);
  k_final<<<1, 128, 0, stream>>>(hfc, out);
}

// Round 2
// 161.253 us; speedup vs baseline: 1.5439x; 1.5439x over previous
//
#include <hip/hip_runtime.h>
#include <math.h>

#define DEVINL __device__ __forceinline__

// Deterministic block reduction of two double accumulators.
// All threads must call; result valid in thread 0 only.
template<int NWAVES>
DEVINL void block_reduce_2d(double& a, double& b) {
  #pragma unroll
  for (int off = 32; off > 0; off >>= 1) {
    a += __shfl_down(a, off, 64);
    b += __shfl_down(b, off, 64);
  }
  __shared__ double sa[NWAVES], sb[NWAVES];
  const int tid = threadIdx.x;
  const int wid = tid >> 6;
  if ((tid & 63) == 0) { sa[wid] = a; sb[wid] = b; }
  __syncthreads();
  if (tid == 0) {
    double ta = 0.0, tb = 0.0;
    #pragma unroll
    for (int w = 0; w < NWAVES; ++w) { ta += sa[w]; tb += sb[w]; }
    a = ta; b = tb;
  }
}

// ---------------- Layer 1: x(16,1,196,3) * w1(128,1,6,1) s=(2,1) -> h1(16,128,96,3), fused BN+ReLU
__global__ __launch_bounds__(256) void k_conv1(
    const float* __restrict__ x, const float* __restrict__ w1,
    const float* __restrict__ g1, const float* __restrict__ b1,
    float* __restrict__ h1) {
  const int co = blockIdx.x;    // 128
  const int tid = threadIdx.x;  // 256
  float wv[6];
  #pragma unroll
  for (int i = 0; i < 6; ++i) wv[i] = w1[co * 6 + i];

  float vals[18];               // 4608 positions / 256 threads
  double s = 0.0, sq = 0.0;
  #pragma unroll
  for (int k = 0; k < 18; ++k) {
    const int p = tid + k * 256;          // (n, ho, wo)
    const int n = p / 288;
    const int r = p - n * 288;
    const int ho = r / 3;
    const int wo = r - ho * 3;
    const float* xb = x + n * 588 + (2 * ho) * 3 + wo;
    float acc = 0.f;
    #pragma unroll
    for (int i = 0; i < 6; ++i) acc += fabsf(xb[i * 3] - wv[i]);
    const float v = -acc;
    vals[k] = v;
    s += (double)v;
    sq += (double)v * (double)v;
  }
  block_reduce_2d<4>(s, sq);
  __shared__ float ssc, ssh;
  if (tid == 0) {
    const double mean = s * (1.0 / 4608.0);
    const double var  = sq * (1.0 / 4608.0) - mean * mean;
    const float rstd = (float)rsqrt(var + 1e-5);
    const float sc = g1[co] * rstd;
    ssc = sc;
    ssh = b1[co] - (float)mean * sc;
  }
  __syncthreads();
  const float sc = ssc, sh = ssh;
  #pragma unroll
  for (int k = 0; k < 18; ++k) {
    const int p = tid + k * 256;
    const int n = p / 288;
    const int r = p - n * 288;
    const int ho = r / 3;
    const int wo = r - ho * 3;
    h1[((n * 128 + co) * 96 + ho) * 3 + wo] = fmaxf(0.f, fmaf(vals[k], sc, sh));
  }
}

// ---------------- Layer 2 partial: h1(16,128,96,3) * w2(256,128,6,1) s=(2,1)
// Grid 256 = 32 co-groups(8) x 8 K-chunks(16 ci). Thread job = (n,hp): 8co x 6pos partial sums.
__global__ __launch_bounds__(384) void k_conv2p(
    const float* __restrict__ h1, const float* __restrict__ w2,
    float* __restrict__ part2) {
  __shared__ float wlds[768];           // [ci 16][co 8][k 6]
  const int bx = blockIdx.x;
  const int cg = bx >> 3, kc = bx & 7;
  const int co0 = cg * 8, ci0 = kc * 16;
  const int tid = threadIdx.x;          // 384
  #pragma unroll
  for (int f = tid; f < 768; f += 384) {
    const int cil = f / 48, rem = f - cil * 48, c = rem / 6, kk = rem - c * 6;
    wlds[f] = w2[(co0 + c) * 768 + (ci0 + cil) * 6 + kk];
  }
  __syncthreads();
  const bool active = tid < 368;        // 16n x 23hp
  int n = 0, hp = 0;
  if (active) { n = tid / 23; hp = tid - n * 23; }
  float acc[8][6];
  #pragma unroll
  for (int c = 0; c < 8; ++c)
    #pragma unroll
    for (int o = 0; o < 6; ++o) acc[c][o] = 0.f;
  if (active) {
    const float4* xb = (const float4*)(h1 + n * 36864 + ci0 * 288 + hp * 12);
    #pragma unroll 1
    for (int ci = 0; ci < 16; ++ci) {
      float xf[24];
      #pragma unroll
      for (int t = 0; t < 6; ++t) {
        const float4 q = xb[ci * 72 + t];
        xf[4 * t + 0] = q.x; xf[4 * t + 1] = q.y; xf[4 * t + 2] = q.z; xf[4 * t + 3] = q.w;
      }
      #pragma unroll
      for (int c = 0; c < 8; ++c) {
        float wv[6];
        #pragma unroll
        for (int k = 0; k < 6; ++k) wv[k] = wlds[ci * 48 + c * 6 + k];
        #pragma unroll
        for (int po = 0; po < 2; ++po)
          #pragma unroll
          for (int wo = 0; wo < 3; ++wo)
            #pragma unroll
            for (int i = 0; i < 6; ++i)
              acc[c][po * 3 + wo] += fabsf(xf[(2 * po + i) * 3 + wo] - wv[i]);
      }
    }
    #pragma unroll
    for (int c = 0; c < 8; ++c)
      #pragma unroll
      for (int po = 0; po < 2; ++po)
        #pragma unroll
        for (int wo = 0; wo < 3; ++wo) {
          const int p = n * 138 + (2 * hp + po) * 3 + wo;
          part2[(size_t)(kc * 256 + co0 + c) * 2208 + p] = acc[c][po * 3 + wo];
        }
  }
}

// ---------------- Layer 2 combine: sum 8 K-partials, BN stats + apply -> h2(16,256,46,3)
__global__ __launch_bounds__(384) void k_combine2(
    const float* __restrict__ part2, const float* __restrict__ g2,
    const float* __restrict__ b2, float* __restrict__ h2) {
  const int co = blockIdx.x;    // 256
  const int tid = threadIdx.x;  // 384, active 368, 6 pos each
  const bool active = tid < 368;
  float v[6];
  double s = 0.0, sq = 0.0;
  #pragma unroll
  for (int k = 0; k < 6; ++k) {
    float sum = 0.f;
    if (active) {
      const int p = tid + k * 368;
      #pragma unroll
      for (int kc = 0; kc < 8; ++kc)
        sum += part2[(size_t)(kc * 256 + co) * 2208 + p];
    }
    const float val = -sum;
    v[k] = val;
    if (active) { s += (double)val; sq += (double)val * (double)val; }
  }
  block_reduce_2d<6>(s, sq);
  __shared__ float ssc, ssh;
  if (tid == 0) {
    const double mean = s * (1.0 / 2208.0);
    const double var  = sq * (1.0 / 2208.0) - mean * mean;
    const float rstd = (float)rsqrt(var + 1e-5);
    const float sc = g2[co] * rstd;
    ssc = sc;
    ssh = b2[co] - (float)mean * sc;
  }
  __syncthreads();
  if (active) {
    const float sc = ssc, sh = ssh;
    #pragma unroll
    for (int k = 0; k < 6; ++k) {
      const int p = tid + k * 368;
      const int n = p / 138, rem = p - n * 138;
      h2[n * 35328 + co * 138 + rem] = fmaxf(0.f, fmaf(v[k], sc, sh));
    }
  }
}

// ---------------- Layer 3 partial: h2(16,256,46,3) * w3(384,256,6,2) s=(2,1)
// Grid 768 = 48 co-groups(8) x 16 K-chunks(16 ci). Thread job = (n,ho): 8co x 2wo partials.
__global__ __launch_bounds__(384) void k_conv3p(
    const float* __restrict__ h2, const float* __restrict__ w3,
    float* __restrict__ part3) {
  __shared__ float wlds[1536];          // [ci 16][co 8][k 12]
  const int bx = blockIdx.x;
  const int cg = bx >> 4, kc = bx & 15;
  const int co0 = cg * 8, ci0 = kc * 16;
  const int tid = threadIdx.x;          // 384
  #pragma unroll
  for (int f = tid; f < 1536; f += 384) {
    const int cil = f / 96, rem = f - cil * 96, c = rem / 12, kk = rem - c * 12;
    wlds[f] = w3[(co0 + c) * 3072 + (ci0 + cil) * 12 + kk];
  }
  __syncthreads();
  const bool active = tid < 336;        // 16n x 21ho
  int n = 0, ho = 0;
  if (active) { n = tid / 21; ho = tid - n * 21; }
  float acc[8][2];
  #pragma unroll
  for (int c = 0; c < 8; ++c) { acc[c][0] = 0.f; acc[c][1] = 0.f; }
  if (active) {
    const float2* xb = (const float2*)(h2 + n * 35328 + ci0 * 138 + ho * 6);
    #pragma unroll 1
    for (int ci = 0; ci < 16; ++ci) {
      float xf[18];
      #pragma unroll
      for (int t = 0; t < 9; ++t) {
        const float2 q = xb[ci * 69 + t];
        xf[2 * t + 0] = q.x; xf[2 * t + 1] = q.y;
      }
      #pragma unroll
      for (int c = 0; c < 8; ++c) {
        float wv[12];
        #pragma unroll
        for (int k = 0; k < 12; ++k) wv[k] = wlds[ci * 96 + c * 12 + k];
        #pragma unroll
        for (int wo = 0; wo < 2; ++wo)
          #pragma unroll
          for (int i = 0; i < 6; ++i)
            #pragma unroll
            for (int j = 0; j < 2; ++j)
              acc[c][wo] += fabsf(xf[i * 3 + wo + j] - wv[i * 2 + j]);
      }
    }
    #pragma unroll
    for (int c = 0; c < 8; ++c)
      #pragma unroll
      for (int wo = 0; wo < 2; ++wo) {
        const int p = n * 42 + ho * 2 + wo;
        part3[(size_t)(kc * 384 + co0 + c) * 672 + p] = acc[c][wo];
      }
  }
}

// ---------------- Layer 3 combine: sum 16 K-partials, BN stats + apply -> h3(16,384,21,2)
__global__ __launch_bounds__(384) void k_combine3(
    const float* __restrict__ part3, const float* __restrict__ g3,
    const float* __restrict__ b3, float* __restrict__ h3) {
  const int co = blockIdx.x;    // 384
  const int tid = threadIdx.x;  // 384, active 336, 2 pos each
  const bool active = tid < 336;
  float v[2];
  double s = 0.0, sq = 0.0;
  #pragma unroll
  for (int k = 0; k < 2; ++k) {
    float sum = 0.f;
    if (active) {
      const int p = tid + k * 336;
      #pragma unroll
      for (int kc = 0; kc < 16; ++kc)
        sum += part3[(size_t)(kc * 384 + co) * 672 + p];
    }
    const float val = -sum;
    v[k] = val;
    if (active) { s += (double)val; sq += (double)val * (double)val; }
  }
  block_reduce_2d<6>(s, sq);
  __shared__ float ssc, ssh;
  if (tid == 0) {
    const double mean = s * (1.0 / 672.0);
    const double var  = sq * (1.0 / 672.0) - mean * mean;
    const float rstd = (float)rsqrt(var + 1e-5);
    const float sc = g3[co] * rstd;
    ssc = sc;
    ssh = b3[co] - (float)mean * sc;
  }
  __syncthreads();
  if (active) {
    const float sc = ssc, sh = ssh;
    #pragma unroll
    for (int k = 0; k < 2; ++k) {
      const int p = tid + k * 336;
      const int n = p / 42, rem = p - n * 42;
      h3[n * 16128 + co * 42 + rem] = fmaxf(0.f, fmaf(v[k], sc, sh));
    }
  }
}

// ---------------- FC partial: h3(16,16128) @ Wfc(6,16128)^T, K split 4 ways
__global__ __launch_bounds__(256) void k_fcp(
    const float* __restrict__ h3, const float* __restrict__ Wfc,
    float* __restrict__ hfcp) {
  const int bx = blockIdx.x;    // 384 = 96 pairs x 4
  const int pair = bx >> 2, q = bx & 3;
  const int n = pair / 6, o = pair - n * 6;
  const float4* xr = (const float4*)(h3 + n * 16128) + q * 1008;
  const float4* wr = (const float4*)(Wfc + o * 16128) + q * 1008;
  float sacc = 0.f;
  for (int k = threadIdx.x; k < 1008; k += 256) {
    const float4 xv = xr[k];
    const float4 wv = wr[k];
    sacc += xv.x * wv.x + xv.y * wv.y + xv.z * wv.z + xv.w * wv.w;
  }
  double d = (double)sacc, dummy = 0.0;
  block_reduce_2d<4>(d, dummy);
  if (threadIdx.x == 0) hfcp[bx] = (float)d;
}

// ---------------- Final: sum FC partials + bias, LayerNorm over 96, per-row L2 norm -> out(16,6)
__global__ __launch_bounds__(128) void k_final(
    const float* __restrict__ hfcp, const float* __restrict__ bfc,
    float* __restrict__ out) {
  __shared__ float ys[96];
  __shared__ float params[2];
  const int tid = threadIdx.x;
  float v = 0.f;
  if (tid < 96) {
    v = hfcp[tid * 4 + 0] + hfcp[tid * 4 + 1] + hfcp[tid * 4 + 2] + hfcp[tid * 4 + 3]
        + bfc[tid % 6];
    ys[tid] = v;
  }
  __syncthreads();
  if (tid == 0) {
    double s = 0.0, sq = 0.0;
    for (int i = 0; i < 96; ++i) { const double t = (double)ys[i]; s += t; sq += t * t; }
    const double mu = s / 96.0;
    const double var = sq / 96.0 - mu * mu;
    params[0] = (float)mu;
    params[1] = (float)rsqrt(var + 1e-5);
  }
  __syncthreads();
  const float y = (v - params[0]) * params[1];
  __syncthreads();
  if (tid < 96) ys[tid] = y;
  __syncthreads();
  if (tid < 96) {
    const int n = tid / 6;
    float ss = 0.f;
    #pragma unroll
    for (int k = 0; k < 6; ++k) { const float t = ys[n * 6 + k]; ss += t * t; }
    const float norm = sqrtf(ss);
    out[tid] = y / fmaxf(norm, 1e-12f);
  }
}

extern "C" void kernel_launch(void* const* d_in, const int* in_sizes, int n_in,
                              void* d_out, int out_size, void* d_ws, size_t ws_size,
                              hipStream_t stream) {
  const float* x   = (const float*)d_in[0];
  const float* w1  = (const float*)d_in[1];
  const float* g1  = (const float*)d_in[2];
  const float* b1  = (const float*)d_in[3];
  const float* w2  = (const float*)d_in[4];
  const float* g2  = (const float*)d_in[5];
  const float* b2  = (const float*)d_in[6];
  const float* w3  = (const float*)d_in[7];
  const float* g3  = (const float*)d_in[8];
  const float* b3  = (const float*)d_in[9];
  const float* Wfc = (const float*)d_in[10];
  const float* bfc = (const float*)d_in[11];

  float* ws   = (float*)d_ws;
  float* h1   = ws;                 // 589824
  float* h2   = h1 + 589824;        // 565248
  float* h3   = h2 + 565248;        // 258048
  float* hfcp = h3 + 258048;        // 384
  float* part = hfcp + 384;         // max(8*256*2208, 16*384*672) = 4521984
  float* out  = (float*)d_out;

  k_conv1   <<<128, 256, 0, stream>>>(x, w1, g1, b1, h1);
  k_conv2p  <<<256, 384, 0, stream>>>(h1, w2, part);
  k_combine2<<<256, 384, 0, stream>>>(part, g2, b2, h2);
  k_conv3p  <<<768, 384, 0, stream>>>(h2, w3, part);
  k_combine3<<<384, 384, 0, stream>>>(part, g3, b3, h3);
  k_fcp     <<<384, 256, 0, stream>>>(h3, Wfc, hfcp);
  k_final   <<<1, 128, 0, stream>>>(hfcp, bfc, out);
}